// Round 6
// baseline (140.558 us; speedup 1.0000x reference)
//
#include <hip/hip_runtime.h>

// Problem constants (from reference): B=4, N=64, S=512, D=128, H=8
#define Bsz 4
#define Ngrp 64
#define Sset 512
#define Din 128
#define Hh 8
#define EST (Sset + 1)  // padded LDS stride for e rows

// DPP-based add over lanes: masks {1,2,7,15} generate the full 16-lane group,
// so 4 steps give every lane the sum of its 16-lane row. Pure VALU (no DS pipe).
#define DPP_QUAD_XOR1 0xB1         // quad_perm [1,0,3,2]
#define DPP_QUAD_XOR2 0x4E         // quad_perm [2,3,0,1]
#define DPP_ROW_HALF_MIRROR 0x141  // lane ^ 7 within 8
#define DPP_ROW_MIRROR 0x140       // lane ^ 15 within 16

template <int CTRL>
__device__ __forceinline__ float dpp_add(float v) {
    int perm = __builtin_amdgcn_update_dpp(0, __float_as_int(v), CTRL, 0xF, 0xF, true);
    return v + __int_as_float(perm);
}

__device__ __forceinline__ float row16_sum(float v) {
    v = dpp_add<DPP_QUAD_XOR1>(v);
    v = dpp_add<DPP_QUAD_XOR2>(v);
    v = dpp_add<DPP_ROW_HALF_MIRROR>(v);
    v = dpp_add<DPP_ROW_MIRROR>(v);
    return v;
}

// -----------------------------------------------------------------------------
// Kernel A: u[h][c] = sum_d W[c, h*D+d] * q[h, d].
// Only the first D rows of W matter: the set-feature half of W, the DeepSets
// MLP, and Wb contribute a per-(b,n,h) constant that cancels in the softmax
// over s.
// -----------------------------------------------------------------------------
__global__ void __launch_bounds__(256) compute_u_kernel(
    const float* __restrict__ W,   // (2D, H*D) row-major
    const float* __restrict__ q,   // (H, D)
    float* __restrict__ u)         // (H, D) out
{
    const int tid = threadIdx.x;   // 0..255
    const int grp = tid >> 4;      // 0..15  (dot within block)
    const int sub = tid & 15;      // 0..15  (position within dot)

    const int idx = blockIdx.x * 16 + grp;   // 0..1023
    const int h = idx >> 7;                  // block-uniform
    const int c = idx & 127;

    const float4* Wr = (const float4*)(W + (size_t)c * (Hh * Din) + (size_t)h * Din);
    const float4* qr = (const float4*)(q + h * Din);
    const float4 w0 = Wr[sub];
    const float4 w1 = Wr[sub + 16];
    const float4 q0 = qr[sub];
    const float4 q1 = qr[sub + 16];

    float v;
    v = w0.x * q0.x;
    v = fmaf(w0.y, q0.y, v);
    v = fmaf(w0.z, q0.z, v);
    v = fmaf(w0.w, q0.w, v);
    v = fmaf(w1.x, q1.x, v);
    v = fmaf(w1.y, q1.y, v);
    v = fmaf(w1.z, q1.z, v);
    v = fmaf(w1.w, q1.w, v);
    v = row16_sum(v);
    if (sub == 0) u[idx] = v;
}

// -----------------------------------------------------------------------------
// Kernel B: exactly the R1 (best: 113.4 us) version. Per (b,n) block:
// e[s][h] = x·u, softmax over s, coalesced store. 1024 threads, depth-2
// register pipeline. This round it is launched 3x (idempotent) as a timing
// probe: delta_dur = 2*(B + gap) resolves whether B is at its ~10.4 us BW
// floor (world 2: overhead-dominated) or at ~2x floor (world 1: optimize B).
// -----------------------------------------------------------------------------
__global__ void __launch_bounds__(1024) attn_softmax_kernel(
    const float* __restrict__ x,    // (B,N,S,D)
    const float* __restrict__ u,    // (H,D)
    float* __restrict__ out)        // (B,N,S,H)
{
    const int bn = blockIdx.x;      // 0..255
    const int tid = threadIdx.x;    // 0..1023
    const int wave = tid >> 6;      // 0..15
    const int lane = tid & 63;
    const int g    = lane >> 4;     // row-group within wave: 0..3
    const int sub  = lane & 15;     // position within row: 0..15

    __shared__ __align__(16) float e_s[Hh * EST];

    const float4* xb = (const float4*)(x + (size_t)bn * Sset * Din);

    // wave handles rows wave*32 .. wave*32+31, 4 rows per pass, 8 passes.
    const int rbase = wave * 32 + g;
    float4 cx0 = xb[(size_t)(rbase + 0) * 32 + sub];
    float4 cx1 = xb[(size_t)(rbase + 0) * 32 + sub + 16];
    float4 nx0 = xb[(size_t)(rbase + 4) * 32 + sub];
    float4 nx1 = xb[(size_t)(rbase + 4) * 32 + sub + 16];

    // ---- preload u fragments (4 KB, L2-hot after kernel A) ----------------
    const float4* u4 = (const float4*)u;
    float4 ua[Hh], ub[Hh];
#pragma unroll
    for (int h = 0; h < Hh; ++h) {
        ua[h] = u4[h * 32 + sub];
        ub[h] = u4[h * 32 + sub + 16];
    }

    // ---- Phase 1: e[s][h] with depth-2 register pipeline ------------------
#pragma unroll
    for (int pass = 0; pass < 8; ++pass) {
        const float4 x0 = cx0, x1 = cx1;
        cx0 = nx0; cx1 = nx1;
        if (pass < 6) {
            const int rn = rbase + (pass + 2) * 4;
            nx0 = xb[(size_t)rn * 32 + sub];
            nx1 = xb[(size_t)rn * 32 + sub + 16];
        }
        const int r = rbase + pass * 4;

        float st = 0.f;
#pragma unroll
        for (int h = 0; h < Hh; ++h) {
            float v;
            v = x0.x * ua[h].x;
            v = fmaf(x0.y, ua[h].y, v);
            v = fmaf(x0.z, ua[h].z, v);
            v = fmaf(x0.w, ua[h].w, v);
            v = fmaf(x1.x, ub[h].x, v);
            v = fmaf(x1.y, ub[h].y, v);
            v = fmaf(x1.z, ub[h].z, v);
            v = fmaf(x1.w, ub[h].w, v);
            v = row16_sum(v);       // DPP: all 16 lanes get the row sum
            if (sub == h) st = v;   // lane h of each group keeps e[r][h]
        }
        if (sub < Hh) e_s[sub * EST + r] = st;
    }
    __syncthreads();

    // ---- Phase 2: softmax over s; wave w (< 8) handles head w -------------
    if (wave < Hh) {
        float* eh = &e_s[wave * EST];

        float m = -1e30f;
#pragma unroll
        for (int k = 0; k < Sset / 64; ++k) m = fmaxf(m, eh[lane + 64 * k]);
#pragma unroll
        for (int off = 32; off >= 1; off >>= 1) m = fmaxf(m, __shfl_xor(m, off, 64));

        float p[Sset / 64];
        float sum = 0.f;
#pragma unroll
        for (int k = 0; k < Sset / 64; ++k) {
            p[k] = __expf(eh[lane + 64 * k] - m);
            sum += p[k];
        }
#pragma unroll
        for (int off = 32; off >= 1; off >>= 1) sum += __shfl_xor(sum, off, 64);

        const float inv = 1.f / sum;
#pragma unroll
        for (int k = 0; k < Sset / 64; ++k) eh[lane + 64 * k] = p[k] * inv;
    }
    __syncthreads();

    // ---- Phase 3: coalesced write out[(bn*S + s)*H + h] -------------------
    {
        const int s = tid >> 1;
        const int half = tid & 1;
        float4 o;
        o.x = e_s[(half * 4 + 0) * EST + s];
        o.y = e_s[(half * 4 + 1) * EST + s];
        o.z = e_s[(half * 4 + 2) * EST + s];
        o.w = e_s[(half * 4 + 3) * EST + s];
        ((float4*)(out + ((size_t)bn * Sset + s) * Hh))[half] = o;
    }
}

extern "C" void kernel_launch(void* const* d_in, const int* in_sizes, int n_in,
                              void* d_out, int out_size, void* d_ws, size_t ws_size,
                              hipStream_t stream) {
    // setup_inputs order: x, w1, b1, w2, b2, w3, b3, W, Wb, q
    const float* x = (const float*)d_in[0];
    const float* W = (const float*)d_in[7];
    const float* q = (const float*)d_in[9];
    float* u = (float*)d_ws;            // H*D floats = 4 KB scratch
    float* out = (float*)d_out;

    compute_u_kernel<<<dim3(64), dim3(256), 0, stream>>>(W, q, u);
    // DIAGNOSTIC ROUND: kernel B launched 3x (idempotent — same out).
    // dur delta vs R1 (113.4 us) = 2*(B_time + launch_gap).
    attn_softmax_kernel<<<dim3(Bsz * Ngrp), dim3(1024), 0, stream>>>(x, u, out);
    attn_softmax_kernel<<<dim3(Bsz * Ngrp), dim3(1024), 0, stream>>>(x, u, out);
    attn_softmax_kernel<<<dim3(Bsz * Ngrp), dim3(1024), 0, stream>>>(x, u, out);
}

// Round 7
// 111.759 us; speedup vs baseline: 1.2577x; 1.2577x over previous
//
#include <hip/hip_runtime.h>

// Problem constants (from reference): B=4, N=64, S=512, D=128, H=8
#define Bsz 4
#define Ngrp 64
#define Sset 512
#define Din 128
#define Hh 8
#define EST (Sset + 1)  // padded LDS stride for e rows

// DPP-based add over lanes: masks {1,2,7,15} generate the full 16-lane group,
// so 4 steps give every lane the sum of its 16-lane row. Pure VALU (no DS pipe).
#define DPP_QUAD_XOR1 0xB1         // quad_perm [1,0,3,2]
#define DPP_QUAD_XOR2 0x4E         // quad_perm [2,3,0,1]
#define DPP_ROW_HALF_MIRROR 0x141  // lane ^ 7 within 8
#define DPP_ROW_MIRROR 0x140       // lane ^ 15 within 16

template <int CTRL>
__device__ __forceinline__ float dpp_add(float v) {
    int perm = __builtin_amdgcn_update_dpp(0, __float_as_int(v), CTRL, 0xF, 0xF, true);
    return v + __int_as_float(perm);
}

__device__ __forceinline__ float row16_sum(float v) {
    v = dpp_add<DPP_QUAD_XOR1>(v);
    v = dpp_add<DPP_QUAD_XOR2>(v);
    v = dpp_add<DPP_ROW_HALF_MIRROR>(v);
    v = dpp_add<DPP_ROW_MIRROR>(v);
    return v;
}

// -----------------------------------------------------------------------------
// Kernel A: u[h][c] = sum_d W[c, h*D+d] * q[h, d].
// Only the first D rows of W matter: the set-feature half of W, the DeepSets
// MLP, and Wb contribute a per-(b,n,h) constant that cancels in the softmax
// over s.
// -----------------------------------------------------------------------------
__global__ void __launch_bounds__(256) compute_u_kernel(
    const float* __restrict__ W,   // (2D, H*D) row-major
    const float* __restrict__ q,   // (H, D)
    float* __restrict__ u)         // (H, D) out
{
    const int tid = threadIdx.x;   // 0..255
    const int grp = tid >> 4;      // 0..15  (dot within block)
    const int sub = tid & 15;      // 0..15  (position within dot)

    const int idx = blockIdx.x * 16 + grp;   // 0..1023
    const int h = idx >> 7;                  // block-uniform
    const int c = idx & 127;

    const float4* Wr = (const float4*)(W + (size_t)c * (Hh * Din) + (size_t)h * Din);
    const float4* qr = (const float4*)(q + h * Din);
    const float4 w0 = Wr[sub];
    const float4 w1 = Wr[sub + 16];
    const float4 q0 = qr[sub];
    const float4 q1 = qr[sub + 16];

    float v;
    v = w0.x * q0.x;
    v = fmaf(w0.y, q0.y, v);
    v = fmaf(w0.z, q0.z, v);
    v = fmaf(w0.w, q0.w, v);
    v = fmaf(w1.x, q1.x, v);
    v = fmaf(w1.y, q1.y, v);
    v = fmaf(w1.z, q1.z, v);
    v = fmaf(w1.w, q1.w, v);
    v = row16_sum(v);
    if (sub == 0) u[idx] = v;
}

// -----------------------------------------------------------------------------
// Kernel B (round 7): R1's two-kernel structure with the phase-1 pipeline at
// depth 4, REGULAR cacheable loads. Matrix so far: fused{d2,d4} = 118.5/118.4
// (depth-insensitive -> no spill issue), two-kernel{d2}=113.4,
// two-kernel{d4+nt}=117.8 (nt cost, L3-bypass on an L3-resident x). This is
// the untested cell: two-kernel{d4, no nt}. Deeper in-flight depth at kernel
// start may shave the cold-HBM window (~900 cy) that depth-2 only half-covers.
// -----------------------------------------------------------------------------
__global__ void __launch_bounds__(1024) attn_softmax_kernel(
    const float* __restrict__ x,    // (B,N,S,D)
    const float* __restrict__ u,    // (H,D)
    float* __restrict__ out)        // (B,N,S,H)
{
    const int bn = blockIdx.x;      // 0..255
    const int tid = threadIdx.x;    // 0..1023
    const int wave = tid >> 6;      // 0..15
    const int lane = tid & 63;
    const int g    = lane >> 4;     // row-group within wave: 0..3
    const int sub  = lane & 15;     // position within row: 0..15

    __shared__ __align__(16) float e_s[Hh * EST];

    const float4* xb = (const float4*)(x + (size_t)bn * Sset * Din);

    // ---- depth-4 pipeline: issue passes 0..3's x loads before anything ----
    // wave handles rows wave*32 .. wave*32+31, 4 rows per pass, 8 passes.
    const int rbase = wave * 32 + g;
    float4 px0[4], px1[4];
#pragma unroll
    for (int i = 0; i < 4; ++i) {
        const float4* xr = xb + (size_t)(rbase + i * 4) * 32;
        px0[i] = xr[sub];
        px1[i] = xr[sub + 16];
    }

    // ---- preload u fragments (4 KB, L2-hot after kernel A) ----------------
    const float4* u4 = (const float4*)u;
    float4 ua[Hh], ub[Hh];
#pragma unroll
    for (int h = 0; h < Hh; ++h) {
        ua[h] = u4[h * 32 + sub];
        ub[h] = u4[h * 32 + sub + 16];
    }

    // ---- Phase 1: e[s][h], software-pipelined depth 4 ---------------------
#pragma unroll
    for (int pass = 0; pass < 8; ++pass) {
        const float4 x0 = px0[pass & 3];
        const float4 x1 = px1[pass & 3];
        if (pass < 4) {   // refill the slot with pass+4's loads
            const float4* xr = xb + (size_t)(rbase + (pass + 4) * 4) * 32;
            px0[pass & 3] = xr[sub];
            px1[pass & 3] = xr[sub + 16];
        }
        const int r = rbase + pass * 4;

        float st = 0.f;
#pragma unroll
        for (int h = 0; h < Hh; ++h) {
            float v;
            v = x0.x * ua[h].x;
            v = fmaf(x0.y, ua[h].y, v);
            v = fmaf(x0.z, ua[h].z, v);
            v = fmaf(x0.w, ua[h].w, v);
            v = fmaf(x1.x, ub[h].x, v);
            v = fmaf(x1.y, ub[h].y, v);
            v = fmaf(x1.z, ub[h].z, v);
            v = fmaf(x1.w, ub[h].w, v);
            v = row16_sum(v);       // DPP: all 16 lanes get the row sum
            if (sub == h) st = v;   // lane h of each group keeps e[r][h]
        }
        if (sub < Hh) e_s[sub * EST + r] = st;
    }
    __syncthreads();

    // ---- Phase 2: softmax over s; wave w (< 8) handles head w -------------
    if (wave < Hh) {
        float* eh = &e_s[wave * EST];

        float m = -1e30f;
#pragma unroll
        for (int k = 0; k < Sset / 64; ++k) m = fmaxf(m, eh[lane + 64 * k]);
#pragma unroll
        for (int off = 32; off >= 1; off >>= 1) m = fmaxf(m, __shfl_xor(m, off, 64));

        float p[Sset / 64];
        float sum = 0.f;
#pragma unroll
        for (int k = 0; k < Sset / 64; ++k) {
            p[k] = __expf(eh[lane + 64 * k] - m);
            sum += p[k];
        }
#pragma unroll
        for (int off = 32; off >= 1; off >>= 1) sum += __shfl_xor(sum, off, 64);

        const float inv = 1.f / sum;
#pragma unroll
        for (int k = 0; k < Sset / 64; ++k) eh[lane + 64 * k] = p[k] * inv;
    }
    __syncthreads();

    // ---- Phase 3: coalesced write out[(bn*S + s)*H + h] -------------------
    {
        const int s = tid >> 1;
        const int half = tid & 1;
        float4 o;
        o.x = e_s[(half * 4 + 0) * EST + s];
        o.y = e_s[(half * 4 + 1) * EST + s];
        o.z = e_s[(half * 4 + 2) * EST + s];
        o.w = e_s[(half * 4 + 3) * EST + s];
        ((float4*)(out + ((size_t)bn * Sset + s) * Hh))[half] = o;
    }
}

extern "C" void kernel_launch(void* const* d_in, const int* in_sizes, int n_in,
                              void* d_out, int out_size, void* d_ws, size_t ws_size,
                              hipStream_t stream) {
    // setup_inputs order: x, w1, b1, w2, b2, w3, b3, W, Wb, q
    const float* x = (const float*)d_in[0];
    const float* W = (const float*)d_in[7];
    const float* q = (const float*)d_in[9];
    float* u = (float*)d_ws;            // H*D floats = 4 KB scratch
    float* out = (float*)d_out;

    compute_u_kernel<<<dim3(64), dim3(256), 0, stream>>>(W, q, u);
    attn_softmax_kernel<<<dim3(Bsz * Ngrp), dim3(1024), 0, stream>>>(x, u, out);
}